// Round 1
// baseline (721.483 us; speedup 1.0000x reference)
//
#include <hip/hip_runtime.h>
#include <hip/hip_bf16.h>
#include <stdint.h>

#define IN_DIM  4096
#define OUT_DIM 4096
#define M_DIM   16384   // 8*2048

#define BM 128
#define BN 128
#define BK 64
#define TM_TILES (M_DIM / BM)     // 128
#define TN_TILES (OUT_DIM / BN)   // 32

typedef float f32x4 __attribute__((ext_vector_type(4)));
typedef short bf16x8 __attribute__((ext_vector_type(8)));
typedef short bf16x4 __attribute__((ext_vector_type(4)));
typedef int   i32x4 __attribute__((ext_vector_type(4)));

__device__ __constant__ float NF4_CODE_D[16] = {
    -1.0f, -0.6961928009986877f, -0.5250730514526367f, -0.39491748809814453f,
    -0.28444138169288635f, -0.18477343022823334f, -0.09105003625154495f, 0.0f,
    0.07958029955625534f, 0.16093020141124725f, 0.24611230194568634f,
    0.33791524171829224f, 0.44070982933044434f, 0.5626170039176941f,
    0.7229568362236023f, 1.0f};

static __device__ __forceinline__ ushort f2bf(float f) {
  union { float f; uint32_t u; } v; v.f = f;
  uint32_t r = v.u + 0x7FFFu + ((v.u >> 16) & 1u);
  return (ushort)(r >> 16);
}

// ---------------- dequant: qweight(int32 0..15) * absmax -> bf16 W[N][K] ----
__global__ void dequant_nf4(const int* __restrict__ q, const float* __restrict__ am,
                            ushort* __restrict__ w) {
  __shared__ float code[16];
  if (threadIdx.x < 16) code[threadIdx.x] = NF4_CODE_D[threadIdx.x];
  __syncthreads();
  size_t t = (size_t)blockIdx.x * blockDim.x + threadIdx.x;
  size_t base = t * 8;
  i32x4 qa = *(const i32x4*)(q + base);
  i32x4 qb = *(const i32x4*)(q + base + 4);
  float s = am[base >> 6];   // 8 consecutive elems always within one 64-block
  bf16x8 o;
  o[0] = (short)f2bf(code[qa[0] & 15] * s);
  o[1] = (short)f2bf(code[qa[1] & 15] * s);
  o[2] = (short)f2bf(code[qa[2] & 15] * s);
  o[3] = (short)f2bf(code[qa[3] & 15] * s);
  o[4] = (short)f2bf(code[qb[0] & 15] * s);
  o[5] = (short)f2bf(code[qb[1] & 15] * s);
  o[6] = (short)f2bf(code[qb[2] & 15] * s);
  o[7] = (short)f2bf(code[qb[3] & 15] * s);
  *(bf16x8*)(w + base) = o;
}

// ---------------- x fp32 -> bf16 ----------------
__global__ void cvt_x(const float* __restrict__ x, ushort* __restrict__ xb) {
  size_t t = (size_t)blockIdx.x * blockDim.x + threadIdx.x;
  size_t base = t * 8;
  f32x4 a = *(const f32x4*)(x + base);
  f32x4 b = *(const f32x4*)(x + base + 4);
  bf16x8 o;
  o[0] = (short)f2bf(a[0]); o[1] = (short)f2bf(a[1]);
  o[2] = (short)f2bf(a[2]); o[3] = (short)f2bf(a[3]);
  o[4] = (short)f2bf(b[0]); o[5] = (short)f2bf(b[1]);
  o[6] = (short)f2bf(b[2]); o[7] = (short)f2bf(b[3]);
  *(bf16x8*)(xb + base) = o;
}

// ---------------- global_load_lds helper (16B direct-to-LDS) ---------------
static __device__ __forceinline__ void llds16(const ushort* g, ushort* l) {
  __builtin_amdgcn_global_load_lds(
      (const __attribute__((address_space(1))) void*)g,
      (__attribute__((address_space(3))) void*)l, 16, 0, 0);
}

// ---------------- GEMM: y[M][N] = Xb[M][K] * W[N][K]^T  (bf16 MFMA) --------
// m97 structure: 128x128 tile, BK=64, 4 waves (2x2), global_load_lds staging,
// linear LDS, 2-barrier K-loop.
template<bool XBF>
__global__ void gemm_k(const float* __restrict__ X, const ushort* __restrict__ Xb,
                       const ushort* __restrict__ W, float* __restrict__ Y) {
  __shared__ ushort As[BM * BK];   // 16 KB
  __shared__ ushort Bs[BN * BK];   // 16 KB

  const int tid  = threadIdx.x;
  const int lane = tid & 63;
  const int wid  = tid >> 6;        // 0..3
  const int wr   = wid >> 1;        // 0..1
  const int wc   = wid & 1;         // 0..1

  // XCD-aware swizzle (nwg = 4096, divisible by 8) then tm-major ordering:
  // 32 consecutive wg share one 128-row x panel (L2), W (33.5MB) lives in L3.
  const int nwg = TM_TILES * TN_TILES;
  const int cpx = nwg >> 3;
  const int bid = blockIdx.x;
  const int wg  = (bid & 7) * cpx + (bid >> 3);
  const int tm  = wg / TN_TILES;
  const int tn  = wg % TN_TILES;

  const size_t row0 = (size_t)tm * BM;
  const size_t col0 = (size_t)tn * BN;

  f32x4 acc[4][4] = {};

  const int arow = lane & 15;       // fragment row within 16
  const int kgrp = lane >> 4;       // 0..3 -> k-subgroup of 8

  // staging geometry for global_load_lds: chunk c = wid*4+i covers LDS rows
  // c*8..c*8+7 (1024B); lane -> row c*8 + (lane>>3), col (lane&7)*8 bf16.
  const int srow = lane >> 3;       // 0..7
  const int scol = (lane & 7) * 8;  // 0..56

  for (int k0 = 0; k0 < IN_DIM; k0 += BK) {
    if (XBF) {
#pragma unroll
      for (int i = 0; i < 4; ++i) {
        const int c = wid * 4 + i;
        llds16(Xb + (row0 + c * 8 + srow) * IN_DIM + k0 + scol, As + c * 512);
      }
    } else {
      // fallback: reg-stage A from fp32 with inline convert
      f32x4 r[8];
#pragma unroll
      for (int i = 0; i < 8; ++i) {
        const int row = i * 16 + (tid >> 4);
        const int col = (tid & 15) * 4;
        r[i] = *(const f32x4*)(X + (row0 + row) * IN_DIM + k0 + col);
      }
#pragma unroll
      for (int i = 0; i < 8; ++i) {
        const int row = i * 16 + (tid >> 4);
        const int col = (tid & 15) * 4;
        bf16x4 o;
        o[0] = (short)f2bf(r[i][0]); o[1] = (short)f2bf(r[i][1]);
        o[2] = (short)f2bf(r[i][2]); o[3] = (short)f2bf(r[i][3]);
        *(bf16x4*)&As[row * BK + col] = o;
      }
    }
#pragma unroll
    for (int i = 0; i < 4; ++i) {
      const int c = wid * 4 + i;
      llds16(W + (col0 + c * 8 + srow) * IN_DIM + k0 + scol, Bs + c * 512);
    }
    __syncthreads();   // drains vmcnt(0): LDS tiles ready

#pragma unroll
    for (int ks = 0; ks < 2; ++ks) {
      bf16x8 a[4], b[4];
#pragma unroll
      for (int m = 0; m < 4; ++m)
        a[m] = *(const bf16x8*)&As[(wr * 64 + m * 16 + arow) * BK + ks * 32 + kgrp * 8];
#pragma unroll
      for (int n = 0; n < 4; ++n)
        b[n] = *(const bf16x8*)&Bs[(wc * 64 + n * 16 + arow) * BK + ks * 32 + kgrp * 8];
#pragma unroll
      for (int m = 0; m < 4; ++m)
#pragma unroll
        for (int n = 0; n < 4; ++n)
          acc[m][n] = __builtin_amdgcn_mfma_f32_16x16x32_bf16(a[m], b[n], acc[m][n], 0, 0, 0);
    }
    __syncthreads();   // all reads done before next stage overwrites
  }

  // C write: D row = (lane>>4)*4 + v, col = lane&15
  float* yb = Y + (row0 + wr * 64) * OUT_DIM + col0 + wc * 64;
  const int crow = (lane >> 4) * 4;
  const int ccol = lane & 15;
#pragma unroll
  for (int m = 0; m < 4; ++m)
#pragma unroll
    for (int n = 0; n < 4; ++n)
#pragma unroll
      for (int v = 0; v < 4; ++v)
        yb[(size_t)(m * 16 + crow + v) * OUT_DIM + n * 16 + ccol] = acc[m][n][v];
}

extern "C" void kernel_launch(void* const* d_in, const int* in_sizes, int n_in,
                              void* d_out, int out_size, void* d_ws, size_t ws_size,
                              hipStream_t stream) {
  const float* x  = (const float*)d_in[0];
  const int*   q  = (const int*)d_in[1];
  const float* am = (const float*)d_in[2];
  float* y = (float*)d_out;

  ushort* w = (ushort*)d_ws;
  const size_t WB = (size_t)OUT_DIM * IN_DIM * sizeof(ushort);       // 33.5 MB
  const size_t XB = (size_t)M_DIM * IN_DIM * sizeof(ushort);         // 134 MB

  dequant_nf4<<<(OUT_DIM * (size_t)IN_DIM) / 8 / 256, 256, 0, stream>>>(q, am, w);

  const int ngrid = TM_TILES * TN_TILES;  // 4096
  if (ws_size >= WB + XB) {
    ushort* xb = (ushort*)((char*)d_ws + WB);
    cvt_x<<<((size_t)M_DIM * IN_DIM) / 8 / 256, 256, 0, stream>>>(x, xb);
    gemm_k<true><<<ngrid, 256, 0, stream>>>(x, xb, w, y);
  } else {
    gemm_k<false><<<ngrid, 256, 0, stream>>>(x, nullptr, w, y);
  }
}

// Round 2
// 633.568 us; speedup vs baseline: 1.1388x; 1.1388x over previous
//
#include <hip/hip_runtime.h>
#include <hip/hip_bf16.h>
#include <stdint.h>

#define IN_DIM  4096
#define OUT_DIM 4096
#define M_DIM   16384   // 8*2048
#define BK      64
#define NT      (IN_DIM / BK)   // 64

typedef float f32x4 __attribute__((ext_vector_type(4)));
typedef short bf16x8 __attribute__((ext_vector_type(8)));
typedef short bf16x4 __attribute__((ext_vector_type(4)));
typedef int   i32x4 __attribute__((ext_vector_type(4)));

__device__ __constant__ float NF4_CODE_D[16] = {
    -1.0f, -0.6961928009986877f, -0.5250730514526367f, -0.39491748809814453f,
    -0.28444138169288635f, -0.18477343022823334f, -0.09105003625154495f, 0.0f,
    0.07958029955625534f, 0.16093020141124725f, 0.24611230194568634f,
    0.33791524171829224f, 0.44070982933044434f, 0.5626170039176941f,
    0.7229568362236023f, 1.0f};

static __device__ __forceinline__ ushort f2bf(float f) {
  union { float f; uint32_t u; } v; v.f = f;
  uint32_t r = v.u + 0x7FFFu + ((v.u >> 16) & 1u);
  return (ushort)(r >> 16);
}

// ---------------- dequant: qweight(int32 0..15) * absmax -> bf16 W[N][K] ----
__global__ void dequant_nf4(const int* __restrict__ q, const float* __restrict__ am,
                            ushort* __restrict__ w) {
  __shared__ float code[16];
  if (threadIdx.x < 16) code[threadIdx.x] = NF4_CODE_D[threadIdx.x];
  __syncthreads();
  size_t t = (size_t)blockIdx.x * blockDim.x + threadIdx.x;
  size_t base = t * 8;
  i32x4 qa = *(const i32x4*)(q + base);
  i32x4 qb = *(const i32x4*)(q + base + 4);
  float s = am[base >> 6];
  bf16x8 o;
  o[0] = (short)f2bf(code[qa[0] & 15] * s);
  o[1] = (short)f2bf(code[qa[1] & 15] * s);
  o[2] = (short)f2bf(code[qa[2] & 15] * s);
  o[3] = (short)f2bf(code[qa[3] & 15] * s);
  o[4] = (short)f2bf(code[qb[0] & 15] * s);
  o[5] = (short)f2bf(code[qb[1] & 15] * s);
  o[6] = (short)f2bf(code[qb[2] & 15] * s);
  o[7] = (short)f2bf(code[qb[3] & 15] * s);
  *(bf16x8*)(w + base) = o;
}

// ---------------- x fp32 -> bf16 ----------------
__global__ void cvt_x(const float* __restrict__ x, ushort* __restrict__ xb) {
  size_t t = (size_t)blockIdx.x * blockDim.x + threadIdx.x;
  size_t base = t * 8;
  f32x4 a = *(const f32x4*)(x + base);
  f32x4 b = *(const f32x4*)(x + base + 4);
  bf16x8 o;
  o[0] = (short)f2bf(a[0]); o[1] = (short)f2bf(a[1]);
  o[2] = (short)f2bf(a[2]); o[3] = (short)f2bf(a[3]);
  o[4] = (short)f2bf(b[0]); o[5] = (short)f2bf(b[1]);
  o[6] = (short)f2bf(b[2]); o[7] = (short)f2bf(b[3]);
  *(bf16x8*)(xb + base) = o;
}

// ---------------- global_load_lds helper (16B direct-to-LDS) ---------------
static __device__ __forceinline__ void llds16(const ushort* g, ushort* l) {
  __builtin_amdgcn_global_load_lds(
      (const __attribute__((address_space(1))) void*)g,
      (__attribute__((address_space(3))) void*)l, 16, 0, 0);
}

// ===========================================================================
// 256x256 8-phase GEMM (T2 swizzle + T3/T4 counted vmcnt + T5 setprio)
// y[M][N] = Xb[M][K] * W[N][K]^T, bf16 MFMA 16x16x32.
// 8 waves (2Mx4N), per-wave output 128x64. LDS 128 KiB: 2 dbuf x (A,B) 32KB.
// Staging schedule per K-tile t (4 phases): {A0(t+1), A1(t+1), B0(t+2),
// B1(t+2)}; B-reads of tile t complete by P2 (read order nh0,nh1), so the
// B(t+2) overwrite of buf[t&1] at P3/P4 is race-free. vmcnt(4) at P4 leaves
// exactly B(t+2)'s 2 half-tiles in flight; everything older (tile t+1) done.
// Swizzle: LDS row r stores 16B-slots permuted by s^=(r&7); applied on the
// global SOURCE col during staging and on the ds_read address (rule #21).
// ===========================================================================
__global__ __launch_bounds__(512, 2) void gemm256(const ushort* __restrict__ Xb,
                                                  const ushort* __restrict__ W,
                                                  float* __restrict__ Y) {
  __shared__ ushort As[2][256 * BK];   // 2 x 32 KB
  __shared__ ushort Bs[2][256 * BK];   // 2 x 32 KB

  const int tid  = threadIdx.x;
  const int lane = tid & 63;
  const int wid  = tid >> 6;        // 0..7
  const int wr   = wid >> 2;        // 0..1 -> M half
  const int wc   = wid & 3;         // 0..3 -> N quarter
  const int l15  = lane & 15;
  const int kg   = lane >> 4;       // 0..3
  const int l7   = lane & 7;

  // bijective XCD swizzle (1024 wgs % 8 == 0), then tn-major within tm:
  // 16 consecutive wgs share one 2MB X panel (fits per-XCD L2); W is
  // L3-resident (33.5 MB).
  const int bid = blockIdx.x;
  const int wg  = (bid & 7) * 128 + (bid >> 3);
  const int tm  = wg >> 4;          // 0..63
  const int tn  = wg & 15;          // 0..15
  const size_t row0 = (size_t)tm * 256;
  const size_t col0 = (size_t)tn * 256;

  // staging: thread covers LDS row srow (per 64-row chunk), slot tid&7.
  // source col slot pre-swizzled so linear LDS holds swizzled layout.
  const int srow  = tid >> 3;                       // 0..63
  const int scol8 = ((tid & 7) ^ (srow & 7)) * 8;   // swizzled src col (elems)
  const int wbase = wid << 9;                       // wave LDS base (ushorts)

  f32x4  acc[8][4] = {};
  bf16x8 a[4][2], b0[2][2], b1[2][2];

#define BARX()  asm volatile("s_barrier" ::: "memory")
#define VMC4()  asm volatile("s_waitcnt vmcnt(4)" ::: "memory")
#define VMC0()  asm volatile("s_waitcnt vmcnt(0)" ::: "memory")
#define PRI1()  __builtin_amdgcn_s_setprio(1)
#define PRI0()  __builtin_amdgcn_s_setprio(0)

#define STAGE_A(kt, h, nb) do { \
    llds16(Xb + (row0 + (h)*128 +  0 + srow) * IN_DIM + (kt)*BK + scol8, \
           &As[nb][(h)*8192 +    0 + wbase]); \
    llds16(Xb + (row0 + (h)*128 + 64 + srow) * IN_DIM + (kt)*BK + scol8, \
           &As[nb][(h)*8192 + 4096 + wbase]); \
  } while (0)

#define STAGE_B(kt, h, nb) do { \
    llds16(W + (col0 + (h)*128 +  0 + srow) * IN_DIM + (kt)*BK + scol8, \
           &Bs[nb][(h)*8192 +    0 + wbase]); \
    llds16(W + (col0 + (h)*128 + 64 + srow) * IN_DIM + (kt)*BK + scol8, \
           &Bs[nb][(h)*8192 + 4096 + wbase]); \
  } while (0)

#define LDA(nb, mh) do { \
    _Pragma("unroll") for (int mi = 0; mi < 4; ++mi) \
    _Pragma("unroll") for (int ks = 0; ks < 2; ++ks) \
      a[mi][ks] = *(const bf16x8*)&As[nb][(wr*128 + (mh)*64 + mi*16 + l15) * BK \
                                          + (((ks*4 + kg) ^ l7) * 8)]; \
  } while (0)

#define LDB(nb, nh, bb) do { \
    _Pragma("unroll") for (int ni = 0; ni < 2; ++ni) \
    _Pragma("unroll") for (int ks = 0; ks < 2; ++ks) \
      bb[ni][ks] = *(const bf16x8*)&Bs[nb][(wc*64 + (nh)*32 + ni*16 + l15) * BK \
                                           + (((ks*4 + kg) ^ l7) * 8)]; \
  } while (0)

#define QUAD(mh, nh, bb) do { \
    _Pragma("unroll") for (int mi = 0; mi < 4; ++mi) \
    _Pragma("unroll") for (int ni = 0; ni < 2; ++ni) \
    _Pragma("unroll") for (int ks = 0; ks < 2; ++ks) \
      acc[(mh)*4 + mi][(nh)*2 + ni] = __builtin_amdgcn_mfma_f32_16x16x32_bf16( \
          a[mi][ks], bb[ni][ks], acc[(mh)*4 + mi][(nh)*2 + ni], 0, 0, 0); \
  } while (0)

// one full K-tile: 4 phases, reads buf `cur`, stages A(tA)->cur^1, B(tB)->cur
#define KTILE(cur, tA, tB) do { \
    LDA(cur, 0); LDB(cur, 0, b0); STAGE_A(tA, 0, (cur)^1); \
    BARX(); PRI1(); QUAD(0, 0, b0); PRI0(); BARX(); \
    LDB(cur, 1, b1); STAGE_A(tA, 1, (cur)^1); \
    BARX(); PRI1(); QUAD(0, 1, b1); PRI0(); BARX(); \
    LDA(cur, 1); STAGE_B(tB, 0, cur); \
    BARX(); PRI1(); QUAD(1, 1, b1); PRI0(); BARX(); \
    STAGE_B(tB, 1, cur); \
    BARX(); PRI1(); QUAD(1, 0, b0); PRI0(); VMC4(); BARX(); \
  } while (0)

  // ---- prologue: tile0 fully + B halves of tile1; keep B(1) in flight ----
  STAGE_B(0, 0, 0); STAGE_B(0, 1, 0);
  STAGE_A(0, 0, 0); STAGE_A(0, 1, 0);
  STAGE_B(1, 0, 1); STAGE_B(1, 1, 1);
  VMC4(); BARX();

  // ---- main loop: pairs of K-tiles (8 phases), full staging ----
#pragma unroll 1
  for (int t = 0; t < NT - 3; t += 2) {
    KTILE(0, t + 1, t + 2);
    KTILE(1, t + 2, t + 3);
  }

  // ---- tile 62 (buf0): stage A(63) only; drain to 0 ----
  LDA(0, 0); LDB(0, 0, b0); STAGE_A(NT - 1, 0, 1);
  BARX(); PRI1(); QUAD(0, 0, b0); PRI0(); BARX();
  LDB(0, 1, b1); STAGE_A(NT - 1, 1, 1);
  BARX(); PRI1(); QUAD(0, 1, b1); PRI0(); BARX();
  LDA(0, 1);
  BARX(); PRI1(); QUAD(1, 1, b1); PRI0(); BARX();
  BARX(); PRI1(); QUAD(1, 0, b0); PRI0(); VMC0(); BARX();

  // ---- tile 63 (buf1): straight-line, no staging ----
  LDA(1, 0); LDB(1, 0, b0); LDB(1, 1, b1);
  QUAD(0, 0, b0); QUAD(0, 1, b1);
  LDA(1, 1);
  QUAD(1, 1, b1); QUAD(1, 0, b0);

#undef KTILE
#undef QUAD
#undef LDB
#undef LDA
#undef STAGE_B
#undef STAGE_A

  // ---- epilogue: C write (row = m*16 + kg*4 + v, col = n*16 + l15) ----
  float* yb = Y + (row0 + wr * 128 + kg * 4) * OUT_DIM + col0 + wc * 64 + l15;
#pragma unroll
  for (int m = 0; m < 8; ++m)
#pragma unroll
    for (int n = 0; n < 4; ++n)
#pragma unroll
      for (int v = 0; v < 4; ++v)
        yb[(size_t)(m * 16 + v) * OUT_DIM + n * 16] = acc[m][n][v];
}

// ---------------- fallback (ws too small): 128^2 fp32-A reg-staged ---------
__global__ void gemm_fb(const float* __restrict__ X, const ushort* __restrict__ W,
                        float* __restrict__ Y) {
  __shared__ ushort Af[128 * 64];
  __shared__ ushort Bf[128 * 64];
  const int tid  = threadIdx.x;
  const int lane = tid & 63;
  const int wid  = tid >> 6;
  const int wr   = wid >> 1, wc = wid & 1;
  const int bid  = blockIdx.x;
  const int tm   = bid / 32, tn = bid % 32;
  const size_t row0 = (size_t)tm * 128, col0 = (size_t)tn * 128;
  f32x4 acc[4][4] = {};
  const int arow = lane & 15, kgrp = lane >> 4;
  const int srow = lane >> 3, scol = (lane & 7) * 8;
  for (int k0 = 0; k0 < IN_DIM; k0 += 64) {
    f32x4 r[8];
#pragma unroll
    for (int i = 0; i < 8; ++i)
      r[i] = *(const f32x4*)(X + (row0 + i * 16 + (tid >> 4)) * IN_DIM + k0 + (tid & 15) * 4);
#pragma unroll
    for (int i = 0; i < 8; ++i) {
      bf16x4 o;
      o[0] = (short)f2bf(r[i][0]); o[1] = (short)f2bf(r[i][1]);
      o[2] = (short)f2bf(r[i][2]); o[3] = (short)f2bf(r[i][3]);
      *(bf16x4*)&Af[(i * 16 + (tid >> 4)) * 64 + (tid & 15) * 4] = o;
    }
#pragma unroll
    for (int i = 0; i < 4; ++i) {
      const int c = wid * 4 + i;
      llds16(W + (col0 + c * 8 + srow) * IN_DIM + k0 + scol, Bf + c * 512);
    }
    __syncthreads();
#pragma unroll
    for (int ks = 0; ks < 2; ++ks) {
      bf16x8 a[4], b[4];
#pragma unroll
      for (int m = 0; m < 4; ++m)
        a[m] = *(const bf16x8*)&Af[(wr * 64 + m * 16 + arow) * 64 + ks * 32 + kgrp * 8];
#pragma unroll
      for (int n = 0; n < 4; ++n)
        b[n] = *(const bf16x8*)&Bf[(wc * 64 + n * 16 + arow) * 64 + ks * 32 + kgrp * 8];
#pragma unroll
      for (int m = 0; m < 4; ++m)
#pragma unroll
        for (int n = 0; n < 4; ++n)
          acc[m][n] = __builtin_amdgcn_mfma_f32_16x16x32_bf16(a[m], b[n], acc[m][n], 0, 0, 0);
    }
    __syncthreads();
  }
  float* yb = Y + (row0 + wr * 64) * OUT_DIM + col0 + wc * 64;
  const int crow = (lane >> 4) * 4, ccol = lane & 15;
#pragma unroll
  for (int m = 0; m < 4; ++m)
#pragma unroll
    for (int n = 0; n < 4; ++n)
#pragma unroll
      for (int v = 0; v < 4; ++v)
        yb[(size_t)(m * 16 + crow + v) * OUT_DIM + n * 16 + ccol] = acc[m][n][v];
}

extern "C" void kernel_launch(void* const* d_in, const int* in_sizes, int n_in,
                              void* d_out, int out_size, void* d_ws, size_t ws_size,
                              hipStream_t stream) {
  const float* x  = (const float*)d_in[0];
  const int*   q  = (const int*)d_in[1];
  const float* am = (const float*)d_in[2];
  float* y = (float*)d_out;

  ushort* w = (ushort*)d_ws;
  const size_t WB = (size_t)OUT_DIM * IN_DIM * sizeof(ushort);   // 33.5 MB
  const size_t XB = (size_t)M_DIM * IN_DIM * sizeof(ushort);     // 134 MB

  dequant_nf4<<<(OUT_DIM * (size_t)IN_DIM) / 8 / 256, 256, 0, stream>>>(q, am, w);

  if (ws_size >= WB + XB) {
    ushort* xb = (ushort*)((char*)d_ws + WB);
    cvt_x<<<((size_t)M_DIM * IN_DIM) / 8 / 256, 256, 0, stream>>>(x, xb);
    gemm256<<<(M_DIM / 256) * (OUT_DIM / 256), 512, 0, stream>>>(xb, w, y);
  } else {
    gemm_fb<<<(M_DIM / 128) * (OUT_DIM / 128), 256, 0, stream>>>(x, w, y);
  }
}

// Round 3
// 584.680 us; speedup vs baseline: 1.2340x; 1.0836x over previous
//
#include <hip/hip_runtime.h>
#include <hip/hip_bf16.h>
#include <stdint.h>

#define IN_DIM  4096
#define OUT_DIM 4096
#define M_DIM   16384   // 8*2048
#define BK      64
#define NT      (IN_DIM / BK)   // 64

typedef float f32x4 __attribute__((ext_vector_type(4)));
typedef short bf16x8 __attribute__((ext_vector_type(8)));
typedef short bf16x4 __attribute__((ext_vector_type(4)));
typedef int   i32x4 __attribute__((ext_vector_type(4)));

__device__ __constant__ float NF4_CODE_D[16] = {
    -1.0f, -0.6961928009986877f, -0.5250730514526367f, -0.39491748809814453f,
    -0.28444138169288635f, -0.18477343022823334f, -0.09105003625154495f, 0.0f,
    0.07958029955625534f, 0.16093020141124725f, 0.24611230194568634f,
    0.33791524171829224f, 0.44070982933044434f, 0.5626170039176941f,
    0.7229568362236023f, 1.0f};

static __device__ __forceinline__ ushort f2bf(float f) {
  union { float f; uint32_t u; } v; v.f = f;
  uint32_t r = v.u + 0x7FFFu + ((v.u >> 16) & 1u);
  return (ushort)(r >> 16);
}

// ---------------- dequant: qweight(int32 0..15) * absmax -> bf16 W[N][K] ----
__global__ void dequant_nf4(const int* __restrict__ q, const float* __restrict__ am,
                            ushort* __restrict__ w) {
  __shared__ float code[16];
  if (threadIdx.x < 16) code[threadIdx.x] = NF4_CODE_D[threadIdx.x];
  __syncthreads();
  size_t t = (size_t)blockIdx.x * blockDim.x + threadIdx.x;
  size_t base = t * 8;
  i32x4 qa = *(const i32x4*)(q + base);
  i32x4 qb = *(const i32x4*)(q + base + 4);
  float s = am[base >> 6];
  bf16x8 o;
  o[0] = (short)f2bf(code[qa[0] & 15] * s);
  o[1] = (short)f2bf(code[qa[1] & 15] * s);
  o[2] = (short)f2bf(code[qa[2] & 15] * s);
  o[3] = (short)f2bf(code[qa[3] & 15] * s);
  o[4] = (short)f2bf(code[qb[0] & 15] * s);
  o[5] = (short)f2bf(code[qb[1] & 15] * s);
  o[6] = (short)f2bf(code[qb[2] & 15] * s);
  o[7] = (short)f2bf(code[qb[3] & 15] * s);
  *(bf16x8*)(w + base) = o;
}

// ---------------- x fp32 -> bf16 ----------------
__global__ void cvt_x(const float* __restrict__ x, ushort* __restrict__ xb) {
  size_t t = (size_t)blockIdx.x * blockDim.x + threadIdx.x;
  size_t base = t * 8;
  f32x4 a = *(const f32x4*)(x + base);
  f32x4 b = *(const f32x4*)(x + base + 4);
  bf16x8 o;
  o[0] = (short)f2bf(a[0]); o[1] = (short)f2bf(a[1]);
  o[2] = (short)f2bf(a[2]); o[3] = (short)f2bf(a[3]);
  o[4] = (short)f2bf(b[0]); o[5] = (short)f2bf(b[1]);
  o[6] = (short)f2bf(b[2]); o[7] = (short)f2bf(b[3]);
  *(bf16x8*)(xb + base) = o;
}

// ---------------- global_load_lds helper (16B direct-to-LDS) ---------------
static __device__ __forceinline__ void llds16(const ushort* g, ushort* l) {
  __builtin_amdgcn_global_load_lds(
      (const __attribute__((address_space(1))) void*)g,
      (__attribute__((address_space(3))) void*)l, 16, 0, 0);
}

// ===========================================================================
// 256x256 GEMM, read-ahead pipelined 4-phase schedule.
// y[M][N] = Xb[M][K] * W[N][K]^T, bf16 MFMA 16x16x32, 8 waves (2Mx4N).
// Per-wave output: rows {wr*64..+63} U {128+wr*64..+63},
//                  cols {wc*32..+31} U {128+wc*32..+31}
// so register buffer aA/aB/b0/b1 maps 1:1 to staged half-tile A0/A1/B0/B1.
// Per K-tile t (4 phases, ONE barrier each):
//  P1: ST A1(t+1)->nxt; vmcnt(4); bar; read b1,aB (for P2/P3); Q00(aA,b0)
//  P2: ST B0(t+1)->nxt; bar;                                   Q01(aA,b1)
//  P3: ST B1(t+1)->nxt; bar;                                   Q11(aB,b1)
//  P4: ST A0(t+2)->cur; vmcnt(4); bar; Q10(aB,b0); read aA,b0 (for t+1)
// vmcnt ledger (per wave, 2 loads per ST): @P1 in-flight {B1(t),A0(t+1),
// A1(t+1)}=6 -> vmcnt(4) drains B1(t). @P4 in-flight {A0..B1(t+1),A0(t+2)}=10
// -> vmcnt(4) leaves {B1(t+1),A0(t+2)}, drains A0/A1/B0(t+1). Each vmcnt
// precedes its barrier; reads follow the barrier => all-wave landing holds.
// Staging writes target regions >=3 barriers past their last reader.
// Swizzle (T2): LDS slot s of row r holds global slot s^(r&7); applied on
// the global source col at staging and on the ds_read address (rule #21).
// ===========================================================================
__global__ __launch_bounds__(512, 2) void gemm256(const ushort* __restrict__ Xb,
                                                  const ushort* __restrict__ W,
                                                  float* __restrict__ Y) {
  __shared__ ushort As[2][256 * BK];   // 2 x 32 KB
  __shared__ ushort Bs[2][256 * BK];   // 2 x 32 KB

  const int tid  = threadIdx.x;
  const int lane = tid & 63;
  const int wid  = tid >> 6;        // 0..7
  const int wr   = wid >> 2;        // 0..1
  const int wc   = wid & 3;         // 0..3
  const int l15  = lane & 15;
  const int kg   = lane >> 4;       // 0..3
  const int l7   = lane & 7;

  // bijective XCD swizzle (1024 wgs, 1024%8==0), tn-major within tm.
  const int bid = blockIdx.x;
  const int wg  = (bid & 7) * 128 + (bid >> 3);
  const int tm  = wg >> 4;          // 0..63
  const int tn  = wg & 15;          // 0..15
  const size_t row0 = (size_t)tm * 256;
  const size_t col0 = (size_t)tn * 256;

  const int srow  = tid >> 3;                       // 0..63
  const int scol8 = ((tid & 7) ^ (srow & 7)) * 8;   // pre-swizzled src col
  const int wbase = wid << 9;                       // wave LDS base (ushorts)

  f32x4  acc[8][4] = {};
  bf16x8 aA[4][2], aB[4][2], b0[2][2], b1[2][2];

#define BARX()  __builtin_amdgcn_s_barrier()
#define VMC(n)  asm volatile("s_waitcnt vmcnt(" #n ")" ::: "memory")
#define PRI1()  __builtin_amdgcn_s_setprio(1)
#define PRI0()  __builtin_amdgcn_s_setprio(0)

#define STAGE_A(kt, h, nb) do { \
    llds16(Xb + (row0 + (h)*128 +  0 + srow) * IN_DIM + (kt)*BK + scol8, \
           &As[nb][(h)*8192 +    0 + wbase]); \
    llds16(Xb + (row0 + (h)*128 + 64 + srow) * IN_DIM + (kt)*BK + scol8, \
           &As[nb][(h)*8192 + 4096 + wbase]); \
  } while (0)

#define STAGE_B(kt, h, nb) do { \
    llds16(W + (col0 + (h)*128 +  0 + srow) * IN_DIM + (kt)*BK + scol8, \
           &Bs[nb][(h)*8192 +    0 + wbase]); \
    llds16(W + (col0 + (h)*128 + 64 + srow) * IN_DIM + (kt)*BK + scol8, \
           &Bs[nb][(h)*8192 + 4096 + wbase]); \
  } while (0)

#define LDA_(dst, nb, mh) do { \
    _Pragma("unroll") for (int mi = 0; mi < 4; ++mi) \
    _Pragma("unroll") for (int ks = 0; ks < 2; ++ks) \
      dst[mi][ks] = *(const bf16x8*)&As[nb][((mh)*128 + wr*64 + mi*16 + l15) * BK \
                                            + (((ks*4 + kg) ^ l7) * 8)]; \
  } while (0)

#define LDB_(dst, nb, nh) do { \
    _Pragma("unroll") for (int ni = 0; ni < 2; ++ni) \
    _Pragma("unroll") for (int ks = 0; ks < 2; ++ks) \
      dst[ni][ks] = *(const bf16x8*)&Bs[nb][((nh)*128 + wc*32 + ni*16 + l15) * BK \
                                            + (((ks*4 + kg) ^ l7) * 8)]; \
  } while (0)

#define QUAD(mh, nh, aR, bR) do { PRI1(); \
    _Pragma("unroll") for (int mi = 0; mi < 4; ++mi) \
    _Pragma("unroll") for (int ni = 0; ni < 2; ++ni) \
    _Pragma("unroll") for (int ks = 0; ks < 2; ++ks) \
      acc[(mh)*4 + mi][(nh)*2 + ni] = __builtin_amdgcn_mfma_f32_16x16x32_bf16( \
          aR[mi][ks], bR[ni][ks], acc[(mh)*4 + mi][(nh)*2 + ni], 0, 0, 0); \
    PRI0(); } while (0)

  // ---- prologue: buf0 full + A0(1); leave A0(1) in flight ----
  STAGE_A(0, 0, 0); STAGE_A(0, 1, 0);
  STAGE_B(0, 0, 0); STAGE_B(0, 1, 0);
  STAGE_A(1, 0, 1);
  VMC(2); BARX();
  LDA_(aA, 0, 0); LDB_(b0, 0, 0);

  // ---- main loop: tiles 0..62 ----
#pragma unroll 1
  for (int t = 0; t < NT - 1; ++t) {
    const int cur = t & 1, nxt = cur ^ 1;
    // P1
    STAGE_A(t + 1, 1, nxt);
    VMC(4); BARX();
    LDB_(b1, cur, 1); LDA_(aB, cur, 1);
    QUAD(0, 0, aA, b0);
    // P2
    STAGE_B(t + 1, 0, nxt);
    BARX();
    QUAD(0, 1, aA, b1);
    // P3
    STAGE_B(t + 1, 1, nxt);
    BARX();
    QUAD(1, 1, aB, b1);
    // P4
    if (t < NT - 2) {
      STAGE_A(t + 2, 0, cur);
      VMC(4);
    } else {
      VMC(2);
    }
    BARX();
    QUAD(1, 0, aB, b0);
    LDA_(aA, nxt, 0); LDB_(b0, nxt, 0);   // for tile t+1 (compiler renames WAR)
  }

  // ---- peeled tile 63 (buf1): no staging ----
  VMC(0); BARX();
  LDB_(b1, 1, 1); LDA_(aB, 1, 1);
  QUAD(0, 0, aA, b0);
  QUAD(0, 1, aA, b1);
  QUAD(1, 1, aB, b1);
  QUAD(1, 0, aB, b0);

#undef QUAD
#undef LDB_
#undef LDA_
#undef STAGE_B
#undef STAGE_A

  // ---- epilogue: row = mh*128 + wr*64 + mi*16 + kg*4 + v,
  //                col = nh*128 + wc*32 + ni*16 + l15
  float* yb = Y + (row0 + wr * 64 + kg * 4) * OUT_DIM + col0 + wc * 32 + l15;
#pragma unroll
  for (int mh = 0; mh < 2; ++mh)
#pragma unroll
    for (int mi = 0; mi < 4; ++mi)
#pragma unroll
      for (int nh = 0; nh < 2; ++nh)
#pragma unroll
        for (int ni = 0; ni < 2; ++ni)
#pragma unroll
          for (int v = 0; v < 4; ++v)
            yb[(size_t)(mh * 128 + mi * 16 + v) * OUT_DIM + nh * 128 + ni * 16] =
                acc[mh * 4 + mi][nh * 2 + ni][v];
}

// ---------------- fallback (ws too small): 128^2 fp32-A reg-staged ---------
__global__ void gemm_fb(const float* __restrict__ X, const ushort* __restrict__ W,
                        float* __restrict__ Y) {
  __shared__ ushort Af[128 * 64];
  __shared__ ushort Bf[128 * 64];
  const int tid  = threadIdx.x;
  const int lane = tid & 63;
  const int wid  = tid >> 6;
  const int wr   = wid >> 1, wc = wid & 1;
  const int bid  = blockIdx.x;
  const int tm   = bid / 32, tn = bid % 32;
  const size_t row0 = (size_t)tm * 128, col0 = (size_t)tn * 128;
  f32x4 acc[4][4] = {};
  const int arow = lane & 15, kgrp = lane >> 4;
  const int srow = lane >> 3, scol = (lane & 7) * 8;
  for (int k0 = 0; k0 < IN_DIM; k0 += 64) {
    f32x4 r[8];
#pragma unroll
    for (int i = 0; i < 8; ++i)
      r[i] = *(const f32x4*)(X + (row0 + i * 16 + (tid >> 4)) * IN_DIM + k0 + (tid & 15) * 4);
#pragma unroll
    for (int i = 0; i < 8; ++i) {
      bf16x4 o;
      o[0] = (short)f2bf(r[i][0]); o[1] = (short)f2bf(r[i][1]);
      o[2] = (short)f2bf(r[i][2]); o[3] = (short)f2bf(r[i][3]);
      *(bf16x4*)&Af[(i * 16 + (tid >> 4)) * 64 + (tid & 15) * 4] = o;
    }
#pragma unroll
    for (int i = 0; i < 4; ++i) {
      const int c = wid * 4 + i;
      llds16(W + (col0 + c * 8 + srow) * IN_DIM + k0 + scol, Bf + c * 512);
    }
    __syncthreads();
#pragma unroll
    for (int ks = 0; ks < 2; ++ks) {
      bf16x8 a[4], b[4];
#pragma unroll
      for (int m = 0; m < 4; ++m)
        a[m] = *(const bf16x8*)&Af[(wr * 64 + m * 16 + arow) * 64 + ks * 32 + kgrp * 8];
#pragma unroll
      for (int n = 0; n < 4; ++n)
        b[n] = *(const bf16x8*)&Bf[(wc * 64 + n * 16 + arow) * 64 + ks * 32 + kgrp * 8];
#pragma unroll
      for (int m = 0; m < 4; ++m)
#pragma unroll
        for (int n = 0; n < 4; ++n)
          acc[m][n] = __builtin_amdgcn_mfma_f32_16x16x32_bf16(a[m], b[n], acc[m][n], 0, 0, 0);
    }
    __syncthreads();
  }
  float* yb = Y + (row0 + wr * 64) * OUT_DIM + col0 + wc * 64;
  const int crow = (lane >> 4) * 4, ccol = lane & 15;
#pragma unroll
  for (int m = 0; m < 4; ++m)
#pragma unroll
    for (int n = 0; n < 4; ++n)
#pragma unroll
      for (int v = 0; v < 4; ++v)
        yb[(size_t)(m * 16 + crow + v) * OUT_DIM + n * 16 + ccol] = acc[m][n][v];
}

extern "C" void kernel_launch(void* const* d_in, const int* in_sizes, int n_in,
                              void* d_out, int out_size, void* d_ws, size_t ws_size,
                              hipStream_t stream) {
  const float* x  = (const float*)d_in[0];
  const int*   q  = (const int*)d_in[1];
  const float* am = (const float*)d_in[2];
  float* y = (float*)d_out;

  ushort* w = (ushort*)d_ws;
  const size_t WB = (size_t)OUT_DIM * IN_DIM * sizeof(ushort);   // 33.5 MB
  const size_t XB = (size_t)M_DIM * IN_DIM * sizeof(ushort);     // 134 MB

  dequant_nf4<<<(OUT_DIM * (size_t)IN_DIM) / 8 / 256, 256, 0, stream>>>(q, am, w);

  if (ws_size >= WB + XB) {
    ushort* xb = (ushort*)((char*)d_ws + WB);
    cvt_x<<<((size_t)M_DIM * IN_DIM) / 8 / 256, 256, 0, stream>>>(x, xb);
    gemm256<<<(M_DIM / 256) * (OUT_DIM / 256), 512, 0, stream>>>(xb, w, y);
  } else {
    gemm_fb<<<(M_DIM / 128) * (OUT_DIM / 128), 256, 0, stream>>>(x, w, y);
  }
}